// Round 7
// baseline (133.586 us; speedup 1.0000x reference)
//
#include <hip/hip_runtime.h>
#include <math.h>

// Problem constants (match reference)
constexpr int B = 4, S = 128, D = 256, TC = 1024;  // TC = D*4 (d,c flattened)
constexpr float EPS = 1e-6f;
constexpr int KW = 64, NSL = 16;     // K staged in 16 slices of 64
constexpr int ROWS = 8, TCOLS = 256; // per-block output tile: 8 rows x 256 t-cols

// ---------------------------------------------------------------------------
// Fully independent blocks: p -> (it = p&15, tt = (p>>4)&3, b = p>>6).
//   Q_hat[i,t] = __expf(qw[c,i,d]) + __expf(qb[t]) + clip(xq[b,i,c])
//   K_hat[j,t] = __expf(kw[c,j,d]) + __expf(kb[t]) + clip(xk[b,j,c])
//   scores[i,j] = sum_t Q_hat*K_hat     (exact: inputs folded into operands)
//   attn = max(softmax_j, EPS); out[i,t] = sum_j attn * V_hat[j,t]
// No workspace, no inter-block sync, no second kernel.
// LDS ~51.5 KB. Grid 256 = 1 block/CU.
// ---------------------------------------------------------------------------
__global__ __launch_bounds__(256)
void qlns_all(const float* __restrict__ query, const float* __restrict__ key_in,
              const float* __restrict__ value,
              const float* __restrict__ qw, const float* __restrict__ qb,
              const float* __restrict__ kw, const float* __restrict__ kb,
              const float* __restrict__ vw, const float* __restrict__ vb,
              float* __restrict__ out)
{
    __shared__ __align__(16) float sh[13184];
    float* wkT  = sh;            // [KW][S+1] = 64x129 (8256); PV reuses [0..8192) as wvS[32][256]
    float* wqs  = sh + 8256;     // [8][KW+4] = 8x68 (544)
    float* att  = sh + 8800;     // [8][128]  (1024)
    float* xkl  = sh + 9824;     // [128][4]
    float* xvl  = sh + 10336;    // [128][4]
    float* xql  = sh + 10848;    // [8][4]
    float* evb  = sh + 10880;    // [256]
    float* ekbF = sh + 11136;    // [1024]
    float* eqbF = sh + 12160;    // [1024]

    const int p = blockIdx.x, tid = threadIdx.x;
    const int it = p & 15, tt = (p >> 4) & 3, b = p >> 6;
    const int i0 = it * ROWS, t0 = tt * TCOLS;

    // ---- phase 0: inputs + bias tables ----
    for (int e = tid; e < S * 4; e += 256) {
        xkl[e] = fmaxf(key_in[b * S * 4 + e], EPS);
        xvl[e] = fmaxf(value[b * S * 4 + e], EPS);
    }
    if (tid < ROWS * 4)
        xql[tid] = fmaxf(query[(b * S + i0) * 4 + tid], EPS);
    for (int e = tid; e < TC; e += 256) {
        ekbF[e] = __expf(kb[e]);
        eqbF[e] = __expf(qb[e]);
    }
    evb[tid] = __expf(vb[t0 + tid]);
    __syncthreads();

    // ---- scores: 16 staged K-slices, acc in registers ----
    const int j = tid & 127, ih = tid >> 7;      // ih: which 4-row half
    float acc[4] = {0.f, 0.f, 0.f, 0.f};

    for (int ks = 0; ks < NSL; ++ks) {
        const int k0 = ks * KW, d0 = k0 >> 2;

        // stage K_hat slice: [4c][128j][16dd] -> wkT[kk][j], kk = dd*4+c
        for (int e = tid; e < 4 * S * 16; e += 256) {
            int c = e >> 11, jj = (e >> 4) & 127, dd = e & 15;
            int kk = dd * 4 + c;
            wkT[kk * (S + 1) + jj] =
                __expf(kw[(c * S + jj) * D + d0 + dd]) + ekbF[k0 + kk] + xkl[jj * 4 + c];
        }
        // stage Q_hat tile: [4c][8i][16dd] -> wqs[i][kk]
        for (int e = tid; e < 4 * ROWS * 16; e += 256) {
            int c = e >> 7, i = (e >> 4) & 7, dd = e & 15;
            int kk = dd * 4 + c;
            wqs[i * (KW + 4) + kk] =
                __expf(qw[(c * S + i0 + i) * D + d0 + dd]) + eqbF[k0 + kk] + xql[i * 4 + c];
        }
        __syncthreads();

        for (int k = 0; k < KW; k += 4) {
            float kv0 = wkT[k * (S + 1) + j],       kv1 = wkT[(k + 1) * (S + 1) + j];
            float kv2 = wkT[(k + 2) * (S + 1) + j], kv3 = wkT[(k + 3) * (S + 1) + j];
            #pragma unroll
            for (int r = 0; r < 4; ++r) {
                float4 q = *(const float4*)&wqs[(ih * 4 + r) * (KW + 4) + k];
                acc[r] += q.x * kv0 + q.y * kv1 + q.z * kv2 + q.w * kv3;
            }
        }
        __syncthreads();   // FMA done before next slice overwrites wkT
    }
    #pragma unroll
    for (int r = 0; r < 4; ++r)
        att[(ih * 4 + r) * S + j] = acc[r];
    __syncthreads();

    // ---- softmax over j per row; wave w handles rows w, w+4 ----
    {
        const int w = tid >> 6, lane = tid & 63;
        #pragma unroll
        for (int rr = 0; rr < ROWS / 4; ++rr) {
            int i = w + rr * 4;
            float s0 = att[i * S + lane], s1 = att[i * S + lane + 64];
            float m = fmaxf(s0, s1);
            #pragma unroll
            for (int o = 32; o > 0; o >>= 1) m = fmaxf(m, __shfl_xor(m, o));
            float e0 = __expf(s0 - m), e1 = __expf(s1 - m);
            float sum = e0 + e1;
            #pragma unroll
            for (int o = 32; o > 0; o >>= 1) sum += __shfl_xor(sum, o);
            float inv = 1.f / sum;
            att[i * S + lane]      = fmaxf(e0 * inv, EPS);   // _to_log(attn) clamp
            att[i * S + lane + 64] = fmaxf(e1 * inv, EPS);
        }
    }
    __syncthreads();

    // ---- PV: V_hat exp'd inline, 4 staged rounds of 32 j-rows ----
    float* wvS = sh;             // [32][256], reuses wkT region
    float oacc[ROWS];
    #pragma unroll
    for (int i = 0; i < ROWS; ++i) oacc[i] = 0.f;

    for (int h = 0; h < 4; ++h) {
        for (int e = tid; e < 32 * TCOLS; e += 256) {
            int jr = e >> 8, tc = e & 255;
            int jj = h * 32 + jr;
            int c = tc & 3, dv = (t0 + tc) >> 2;
            wvS[jr * TCOLS + tc] =
                __expf(vw[(c * S + jj) * D + dv]) + evb[tc] + xvl[jj * 4 + c];
        }
        __syncthreads();
        for (int jj = 0; jj < 32; jj += 4) {
            float v0 = wvS[jj * TCOLS + tid],       v1 = wvS[(jj + 1) * TCOLS + tid];
            float v2 = wvS[(jj + 2) * TCOLS + tid], v3 = wvS[(jj + 3) * TCOLS + tid];
            int jb = h * 32 + jj;
            #pragma unroll
            for (int i = 0; i < ROWS; ++i) {
                float4 a = *(const float4*)&att[i * S + jb];
                oacc[i] += a.x * v0 + a.y * v1 + a.z * v2 + a.w * v3;
            }
        }
        __syncthreads();
    }

    float* ob = out + (size_t)(b * S + i0) * TC + t0 + tid;
    #pragma unroll
    for (int i = 0; i < ROWS; ++i) ob[i * TC] = oacc[i];
}

extern "C" void kernel_launch(void* const* d_in, const int* in_sizes, int n_in,
                              void* d_out, int out_size, void* d_ws, size_t ws_size,
                              hipStream_t stream)
{
    const float* query  = (const float*)d_in[0];
    const float* key_in = (const float*)d_in[1];
    const float* value  = (const float*)d_in[2];
    const float* qw = (const float*)d_in[3];
    const float* qb = (const float*)d_in[4];
    const float* kw = (const float*)d_in[5];
    const float* kb = (const float*)d_in[6];
    const float* vw = (const float*)d_in[7];
    const float* vb = (const float*)d_in[8];
    float* out = (float*)d_out;

    qlns_all<<<256, 256, 0, stream>>>(query, key_in, value,
                                      qw, qb, kw, kb, vw, vb, out);
}

// Round 8
// 23.467 us; speedup vs baseline: 5.6924x; 5.6924x over previous
//
#include <hip/hip_runtime.h>
#include <math.h>

// Problem constants (match reference)
constexpr int B = 4, S = 128, D = 256, TC = 1024;  // TC = D*4 (d,c flattened)
constexpr float EPS = 1e-6f;
constexpr int KS = 16, KW = 64;      // split-K for G (KS*KW = TC)
constexpr int ROWS = 8, TCOLS = 256; // kB tiling
constexpr int JR = 32;               // PV round size (j-rows per staged round)

// ws layout (floats): Wv[S][TC] | SWq[S*4] | SWk[S*4] | Gpart[KS][S][S]

// ---------------------------------------------------------------------------
// kA: 256 independent blocks, two roles (R5 math, latency-optimized staging).
//  blk <  128: (it = blk>>4, ks = blk&15): Gpart[ks][i0..i0+15][:] with
//     Wq/Wk exp'd inline. All global loads batched as float4 into registers
//     BEFORE exp/store -> one latency window.
//  blk >= 128: s = blk-128: Wv row + SWq/SWk row (unchanged from R5).
// ---------------------------------------------------------------------------
__global__ __launch_bounds__(256)
void kA(const float* __restrict__ qw, const float* __restrict__ qb,
        const float* __restrict__ kw, const float* __restrict__ kb,
        const float* __restrict__ vw, const float* __restrict__ vb,
        float* __restrict__ Wv, float* __restrict__ SWq, float* __restrict__ SWk,
        float* __restrict__ Gpart)
{
    __shared__ __align__(16) float wkT[KW][S + 1];   // exp'd K slice, transposed
    __shared__ __align__(16) float wqs[16][KW + 4];  // exp'd Q tile, 16B-aligned rows
    __shared__ float ekb[KW], eqb[KW];
    __shared__ float redq[256], redk[256];

    const int blk = blockIdx.x, tid = threadIdx.x;

    if (blk < 128) {
        const int it = blk >> 4, ks = blk & 15;
        const int k0 = ks * KW, d0 = k0 >> 2, i0 = it * 16;

        // issue ALL global loads first (independent, pipelined)
        float4 kv4[8];
        #pragma unroll
        for (int r = 0; r < 8; ++r) {
            int e = r * 256 + tid;                 // [4c][128j][4dd4]
            int dd4 = e & 3, j = (e >> 2) & 127, c = e >> 9;
            kv4[r] = *(const float4*)&kw[(c * S + j) * D + d0 + dd4 * 4];
        }
        float4 q4;
        {
            int dd4 = tid & 3, i = (tid >> 2) & 15, c = tid >> 6;
            q4 = *(const float4*)&qw[(c * S + i0 + i) * D + d0 + dd4 * 4];
        }
        if (tid < KW) {
            ekb[tid] = __expf(kb[k0 + tid]);
            eqb[tid] = __expf(qb[k0 + tid]);
        }
        __syncthreads();   // ekb/eqb ready

        // exp + LDS store (kk = dd*4+c = dd4*16 + 4q + c); 2 lanes/bank -> free
        #pragma unroll
        for (int r = 0; r < 8; ++r) {
            int e = r * 256 + tid;
            int dd4 = e & 3, j = (e >> 2) & 127, c = e >> 9;
            int kkb = dd4 * 16 + c;
            wkT[kkb][j]      = __expf(kv4[r].x) + ekb[kkb];
            wkT[kkb + 4][j]  = __expf(kv4[r].y) + ekb[kkb + 4];
            wkT[kkb + 8][j]  = __expf(kv4[r].z) + ekb[kkb + 8];
            wkT[kkb + 12][j] = __expf(kv4[r].w) + ekb[kkb + 12];
        }
        {
            int dd4 = tid & 3, i = (tid >> 2) & 15, c = tid >> 6;
            int kkb = dd4 * 16 + c;
            wqs[i][kkb]      = __expf(q4.x) + eqb[kkb];
            wqs[i][kkb + 4]  = __expf(q4.y) + eqb[kkb + 4];
            wqs[i][kkb + 8]  = __expf(q4.z) + eqb[kkb + 8];
            wqs[i][kkb + 12] = __expf(q4.w) + eqb[kkb + 12];
        }
        __syncthreads();

        const int j = tid & 127, ih = tid >> 7;
        float acc[8] = {0.f,0.f,0.f,0.f,0.f,0.f,0.f,0.f};
        for (int k = 0; k < KW; k += 4) {
            float kv0 = wkT[k][j], kv1 = wkT[k + 1][j];
            float kv2 = wkT[k + 2][j], kv3 = wkT[k + 3][j];
            #pragma unroll
            for (int r = 0; r < 8; ++r) {
                float4 q = *(const float4*)&wqs[ih * 8 + r][k];   // broadcast b128
                acc[r] += q.x * kv0 + q.y * kv1 + q.z * kv2 + q.w * kv3;
            }
        }
        #pragma unroll
        for (int r = 0; r < 8; ++r) {
            int i = i0 + ih * 8 + r;
            Gpart[(ks * S + i) * S + j] = acc[r];
        }
    } else {
        const int s = blk - 128;
        float pq = 0.f, pk = 0.f;
        #pragma unroll
        for (int r = 0; r < 4; ++r) {
            int t = r * 256 + tid;
            int c = t & 3, d = t >> 2;
            int wi = (c * S + s) * D + d;            // [4,S,D]
            pq += __expf(qw[wi]) + __expf(qb[t]);
            pk += __expf(kw[wi]) + __expf(kb[t]);
            Wv[s * TC + t] = __expf(vw[wi]) + __expf(vb[t]);
        }
        redq[tid] = pq; redk[tid] = pk;
        __syncthreads();
        if (tid < 4) {
            float sq = 0.f, sk = 0.f;
            for (int u = tid; u < 256; u += 4) { sq += redq[u]; sk += redk[u]; }
            SWq[s * 4 + tid] = sq; SWk[s * 4 + tid] = sk;
        }
    }
}

// ---------------------------------------------------------------------------
// kB: fused scores + softmax + PV (R5 math; load-latency optimized).
//  scores: thread owns (i = tid>>5, j4 = (tid&31)*4); 16 independent float4
//  Gpart loads summed in ks order (same per-element order as R5).
//  PV: 4 rounds of 32 j-rows, register-prefetched one round ahead; round 0
//  loads issue before softmax.
// ---------------------------------------------------------------------------
__global__ __launch_bounds__(256)
void kB(const float* __restrict__ query, const float* __restrict__ key_in,
        const float* __restrict__ value,
        const float* __restrict__ Wv, const float* __restrict__ SWq,
        const float* __restrict__ SWk, const float* __restrict__ Gpart,
        float* __restrict__ out)
{
    __shared__ __align__(16) float att[ROWS][S];      // 4 KB
    __shared__ __align__(16) float wvS[JR][TCOLS];    // 32 KB staged round
    __shared__ __align__(16) float xkl[S][4], xvl[S][4], swkl[S][4];
    __shared__ float xql[ROWS][4], swql[ROWS][4];
    const int tt = blockIdx.x, i0 = blockIdx.y * ROWS, b = blockIdx.z;
    const int tid = threadIdx.x;

    for (int e = tid; e < S * 4; e += 256) {
        xkl[e >> 2][e & 3]  = fmaxf(key_in[b * S * 4 + e], EPS);
        xvl[e >> 2][e & 3]  = fmaxf(value[b * S * 4 + e], EPS);
        swkl[e >> 2][e & 3] = SWk[e];
    }
    if (tid < ROWS * 4) {
        xql[tid >> 2][tid & 3]  = fmaxf(query[(b * S + i0) * 4 + tid], EPS);
        swql[tid >> 2][tid & 3] = SWq[i0 * 4 + tid];
    }

    // scores: 16 independent float4 loads, summed in ks order
    const int si = tid >> 5, sj4 = (tid & 31) * 4;
    float4 g = make_float4(0.f, 0.f, 0.f, 0.f);
    #pragma unroll
    for (int ks = 0; ks < KS; ++ks) {
        float4 t = *(const float4*)&Gpart[(size_t)(ks * S + i0 + si) * S + sj4];
        g.x += t.x; g.y += t.y; g.z += t.z; g.w += t.w;
    }
    __syncthreads();   // xql/xkl/swkl ready
    {
        float sc[4] = {g.x, g.y, g.z, g.w};
        #pragma unroll
        for (int q = 0; q < 4; ++q) {
            int j = sj4 + q;
            #pragma unroll
            for (int c = 0; c < 4; ++c)
                sc[q] += (float)D * xql[si][c] * xkl[j][c]
                       + xql[si][c] * swkl[j][c] + swql[si][c] * xkl[j][c];
        }
        *(float4*)&att[si][sj4] = make_float4(sc[0], sc[1], sc[2], sc[3]);
    }

    // prefetch PV round 0 (independent of att)
    float4 pf[8];
    #pragma unroll
    for (int r = 0; r < 8; ++r) {
        int e = r * 256 + tid;                 // [32jr][64c4]
        int jr = e >> 6, c4 = (e & 63) * 4;
        pf[r] = *(const float4*)&Wv[(size_t)jr * TC + tt * TCOLS + c4];
    }
    __syncthreads();   // att complete

    // softmax over j per row; wave w handles rows w, w+4
    {
        const int w = tid >> 6, lane = tid & 63;
        #pragma unroll
        for (int rr = 0; rr < ROWS / 4; ++rr) {
            int i = w + rr * 4;
            float s0 = att[i][lane], s1 = att[i][lane + 64];
            float m = fmaxf(s0, s1);
            #pragma unroll
            for (int o = 32; o > 0; o >>= 1) m = fmaxf(m, __shfl_xor(m, o));
            float e0 = __expf(s0 - m), e1 = __expf(s1 - m);
            float sum = e0 + e1;
            #pragma unroll
            for (int o = 32; o > 0; o >>= 1) sum += __shfl_xor(sum, o);
            float inv = 1.f / sum;
            att[i][lane]      = fmaxf(e0 * inv, EPS);   // _to_log(attn) clamp
            att[i][lane + 64] = fmaxf(e1 * inv, EPS);
        }
    }

    float acc[ROWS];
    #pragma unroll
    for (int i = 0; i < ROWS; ++i) acc[i] = 0.f;

    for (int h = 0; h < 4; ++h) {
        // store round h (add xv at store time), prefetch round h+1
        #pragma unroll
        for (int r = 0; r < 8; ++r) {
            int e = r * 256 + tid;
            int jr = e >> 6, c4 = (e & 63) * 4;
            float4 xv = *(const float4*)&xvl[h * JR + jr][0];
            float4 o;
            o.x = pf[r].x + xv.x; o.y = pf[r].y + xv.y;
            o.z = pf[r].z + xv.z; o.w = pf[r].w + xv.w;
            *(float4*)&wvS[jr][c4] = o;
        }
        if (h < 3) {
            #pragma unroll
            for (int r = 0; r < 8; ++r) {
                int e = r * 256 + tid;
                int jr = e >> 6, c4 = (e & 63) * 4;
                pf[r] = *(const float4*)&Wv[(size_t)((h + 1) * JR + jr) * TC + tt * TCOLS + c4];
            }
        }
        __syncthreads();   // wvS (and, for h=0, softmax'd att) visible
        for (int jj = 0; jj < JR; jj += 4) {
            float v0 = wvS[jj][tid],     v1 = wvS[jj + 1][tid];
            float v2 = wvS[jj + 2][tid], v3 = wvS[jj + 3][tid];
            int jb = h * JR + jj;
            #pragma unroll
            for (int i = 0; i < ROWS; ++i) {
                float4 a = *(const float4*)&att[i][jb];   // broadcast b128
                acc[i] += a.x * v0 + a.y * v1 + a.z * v2 + a.w * v3;
            }
        }
        __syncthreads();   // compute done before next round overwrites wvS
    }

    float* ob = out + (size_t)(b * S + i0) * TC + tt * TCOLS + tid;
    #pragma unroll
    for (int i = 0; i < ROWS; ++i) ob[i * TC] = acc[i];
}

extern "C" void kernel_launch(void* const* d_in, const int* in_sizes, int n_in,
                              void* d_out, int out_size, void* d_ws, size_t ws_size,
                              hipStream_t stream)
{
    const float* query  = (const float*)d_in[0];
    const float* key_in = (const float*)d_in[1];
    const float* value  = (const float*)d_in[2];
    const float* qw = (const float*)d_in[3];
    const float* qb = (const float*)d_in[4];
    const float* kw = (const float*)d_in[5];
    const float* kb = (const float*)d_in[6];
    const float* vw = (const float*)d_in[7];
    const float* vb = (const float*)d_in[8];
    float* out = (float*)d_out;

    float* Wv    = (float*)d_ws;
    float* SWq   = Wv + (size_t)S * TC;
    float* SWk   = SWq + S * 4;
    float* Gpart = SWk + S * 4;          // [KS][S][S] = 1 MB

    kA<<<256, 256, 0, stream>>>(qw, qb, kw, kb, vw, vb, Wv, SWq, SWk, Gpart);
    kB<<<dim3(TC / TCOLS, S / ROWS, B), 256, 0, stream>>>(
        query, key_in, value, Wv, SWq, SWk, Gpart, out);
}

// Round 9
// 19.012 us; speedup vs baseline: 7.0262x; 1.2343x over previous
//
#include <hip/hip_runtime.h>
#include <math.h>

// Problem constants (match reference)
constexpr int B = 4, S = 128, D = 256, TC = 1024;  // TC = D*4 (d,c flattened)
constexpr float EPS = 1e-6f;
constexpr int KS = 8, KW = 128;      // split-K for G (KS*KW = TC)
constexpr int ROWS = 8, TCOLS = 256; // kB tiling
constexpr int JR = 32;               // PV round size (j-rows per round)

// ws layout (floats): Wv[S][TC] | SWq[S*4] | SWk[S*4] | Gpart[KS][S][S]

// ---------------------------------------------------------------------------
// kA: 256 independent blocks, two roles.
//  blk <  128: (it = blk>>3, ks = blk&7): Gpart[ks][i0..i0+7][:], K-depth 128,
//     Wq/Wk exp'd inline; all global loads batched to registers first.
//  blk >= 128: s = blk-128: Wv row + SWq/SWk row (R5 math, validated).
// ---------------------------------------------------------------------------
__global__ __launch_bounds__(256)
void kA(const float* __restrict__ qw, const float* __restrict__ qb,
        const float* __restrict__ kw, const float* __restrict__ kb,
        const float* __restrict__ vw, const float* __restrict__ vb,
        float* __restrict__ Wv, float* __restrict__ SWq, float* __restrict__ SWk,
        float* __restrict__ Gpart)
{
    __shared__ __align__(16) float wkT[KW][S + 1];    // 66 KB exp'd K slice, transposed
    __shared__ __align__(16) float wqs[ROWS][KW + 4]; // exp'd Q tile, 16B-aligned rows
    __shared__ float ekb[KW], eqb[KW];
    __shared__ float redq[256], redk[256];

    const int blk = blockIdx.x, tid = threadIdx.x;

    if (blk < 128) {
        const int it = blk >> 3, ks = blk & 7;
        const int k0 = ks * KW, d0 = k0 >> 2, i0 = it * ROWS;

        // batch ALL global loads into registers (one latency window)
        float4 kv4[16];
        #pragma unroll
        for (int r = 0; r < 16; ++r) {
            int e = r * 256 + tid;                 // [4c][128j][8dd4]
            int dd4 = e & 7, j = (e >> 3) & 127, c = (e >> 10) & 3;
            kv4[r] = *(const float4*)&kw[(c * S + j) * D + d0 + dd4 * 4];
        }
        float4 q4;
        {
            int dd4 = tid & 7, i = (tid >> 3) & 7, c = tid >> 6;
            q4 = *(const float4*)&qw[(c * S + i0 + i) * D + d0 + dd4 * 4];
        }
        if (tid < KW) {
            ekb[tid] = __expf(kb[k0 + tid]);
            eqb[tid] = __expf(qb[k0 + tid]);
        }
        __syncthreads();   // ekb/eqb ready

        // exp + LDS store; kk = dd*4+c = dd4*16 + qd*4 + c
        #pragma unroll
        for (int r = 0; r < 16; ++r) {
            int e = r * 256 + tid;
            int dd4 = e & 7, j = (e >> 3) & 127, c = (e >> 10) & 3;
            int kkb = dd4 * 16 + c;
            wkT[kkb][j]      = __expf(kv4[r].x) + ekb[kkb];
            wkT[kkb + 4][j]  = __expf(kv4[r].y) + ekb[kkb + 4];
            wkT[kkb + 8][j]  = __expf(kv4[r].z) + ekb[kkb + 8];
            wkT[kkb + 12][j] = __expf(kv4[r].w) + ekb[kkb + 12];
        }
        {
            int dd4 = tid & 7, i = (tid >> 3) & 7, c = tid >> 6;
            int kkb = dd4 * 16 + c;
            wqs[i][kkb]      = __expf(q4.x) + eqb[kkb];
            wqs[i][kkb + 4]  = __expf(q4.y) + eqb[kkb + 4];
            wqs[i][kkb + 8]  = __expf(q4.z) + eqb[kkb + 8];
            wqs[i][kkb + 12] = __expf(q4.w) + eqb[kkb + 12];
        }
        __syncthreads();

        const int j = tid & 127, ih = tid >> 7;   // ih: 4-row half
        float acc[4] = {0.f, 0.f, 0.f, 0.f};
        for (int k = 0; k < KW; k += 4) {
            float kv0 = wkT[k][j], kv1 = wkT[k + 1][j];
            float kv2 = wkT[k + 2][j], kv3 = wkT[k + 3][j];
            #pragma unroll
            for (int r = 0; r < 4; ++r) {
                float4 q = *(const float4*)&wqs[ih * 4 + r][k];  // broadcast b128
                acc[r] += q.x * kv0 + q.y * kv1 + q.z * kv2 + q.w * kv3;
            }
        }
        #pragma unroll
        for (int r = 0; r < 4; ++r)
            Gpart[(size_t)(ks * S + i0 + ih * 4 + r) * S + j] = acc[r];
    } else {
        const int s = blk - 128;
        float pq = 0.f, pk = 0.f;
        #pragma unroll
        for (int r = 0; r < 4; ++r) {
            int t = r * 256 + tid;
            int c = t & 3, d = t >> 2;
            int wi = (c * S + s) * D + d;            // [4,S,D]
            pq += __expf(qw[wi]) + __expf(qb[t]);
            pk += __expf(kw[wi]) + __expf(kb[t]);
            Wv[s * TC + t] = __expf(vw[wi]) + __expf(vb[t]);
        }
        redq[tid] = pq; redk[tid] = pk;
        __syncthreads();
        if (tid < 4) {
            float sq = 0.f, sk = 0.f;
            for (int u = tid; u < 256; u += 4) { sq += redq[u]; sk += redk[u]; }
            SWq[s * 4 + tid] = sq; SWk[s * 4 + tid] = sk;
        }
    }
}

// ---------------------------------------------------------------------------
// kB: fused scores + softmax + register-resident PV.
//  scores: thread (si=tid>>5, sj4=(tid&31)*4), 8 independent Gpart float4s.
//  softmax writes transposed attn attT[j][i].
//  PV: thread owns t-cols c4=(tid&63)*4 and j-set {h*32 + r*4 + w}, w=wave.
//  FMA entirely from registers + wave-uniform attT/xvl broadcasts; one
//  cross-wave LDS reduction at the end. No staging barriers.
// ---------------------------------------------------------------------------
__global__ __launch_bounds__(256)
void kB(const float* __restrict__ query, const float* __restrict__ key_in,
        const float* __restrict__ value,
        const float* __restrict__ Wv, const float* __restrict__ SWq,
        const float* __restrict__ SWk, const float* __restrict__ Gpart,
        float* __restrict__ out)
{
    __shared__ __align__(16) float att[ROWS][S];        // pre-softmax scores
    __shared__ __align__(16) float attT[S][ROWS];       // softmax'd, transposed
    __shared__ __align__(16) float red[4][ROWS][64][4]; // 32 KB cross-wave partials
    __shared__ __align__(16) float xkl[S][4], xvl[S][4], swkl[S][4];
    __shared__ float xql[ROWS][4], swql[ROWS][4];

    const int tt = blockIdx.x, i0 = blockIdx.y * ROWS, b = blockIdx.z;
    const int tid = threadIdx.x;
    const int w = tid >> 6, c4 = (tid & 63) * 4;

    for (int e = tid; e < S * 4; e += 256) {
        xkl[e >> 2][e & 3]  = fmaxf(key_in[b * S * 4 + e], EPS);
        xvl[e >> 2][e & 3]  = fmaxf(value[b * S * 4 + e], EPS);
        swkl[e >> 2][e & 3] = SWk[e];
    }
    if (tid < ROWS * 4) {
        xql[tid >> 2][tid & 3]  = fmaxf(query[(b * S + i0) * 4 + tid], EPS);
        swql[tid >> 2][tid & 3] = SWq[i0 * 4 + tid];
    }

    // scores: 8 independent float4 Gpart loads (ks ascending)
    const int si = tid >> 5, sj4 = (tid & 31) * 4;
    float4 g = make_float4(0.f, 0.f, 0.f, 0.f);
    #pragma unroll
    for (int ks = 0; ks < KS; ++ks) {
        float4 t = *(const float4*)&Gpart[(size_t)(ks * S + i0 + si) * S + sj4];
        g.x += t.x; g.y += t.y; g.z += t.z; g.w += t.w;
    }

    // prefetch PV round 0: j = r*4 + w, t-cols c4..c4+3
    float4 pf[8];
    #pragma unroll
    for (int r = 0; r < 8; ++r)
        pf[r] = *(const float4*)&Wv[(size_t)(r * 4 + w) * TC + tt * TCOLS + c4];

    __syncthreads();   // xql/xkl/swkl ready
    {
        float sc[4] = {g.x, g.y, g.z, g.w};
        #pragma unroll
        for (int q = 0; q < 4; ++q) {
            int j = sj4 + q;
            #pragma unroll
            for (int c = 0; c < 4; ++c)
                sc[q] += (float)D * xql[si][c] * xkl[j][c]
                       + xql[si][c] * swkl[j][c] + swql[si][c] * xkl[j][c];
        }
        *(float4*)&att[si][sj4] = make_float4(sc[0], sc[1], sc[2], sc[3]);
    }
    __syncthreads();   // att complete

    // softmax over j per row; wave w handles rows w, w+4; write transposed
    {
        const int lane = tid & 63;
        #pragma unroll
        for (int rr = 0; rr < ROWS / 4; ++rr) {
            int i = w + rr * 4;
            float s0 = att[i][lane], s1 = att[i][lane + 64];
            float m = fmaxf(s0, s1);
            #pragma unroll
            for (int o = 32; o > 0; o >>= 1) m = fmaxf(m, __shfl_xor(m, o));
            float e0 = __expf(s0 - m), e1 = __expf(s1 - m);
            float sum = e0 + e1;
            #pragma unroll
            for (int o = 32; o > 0; o >>= 1) sum += __shfl_xor(sum, o);
            float inv = 1.f / sum;
            attT[lane][i]      = fmaxf(e0 * inv, EPS);   // _to_log(attn) clamp
            attT[lane + 64][i] = fmaxf(e1 * inv, EPS);
        }
    }
    __syncthreads();   // attT ready

    // PV: register-resident, no per-round barriers
    float4 acc4[ROWS];
    #pragma unroll
    for (int i = 0; i < ROWS; ++i) acc4[i] = make_float4(0.f, 0.f, 0.f, 0.f);

    for (int h = 0; h < 4; ++h) {
        float4 pfn[8];
        if (h < 3) {
            #pragma unroll
            for (int r = 0; r < 8; ++r)
                pfn[r] = *(const float4*)&Wv[(size_t)((h + 1) * JR + r * 4 + w) * TC
                                             + tt * TCOLS + c4];
        }
        #pragma unroll
        for (int r = 0; r < 8; ++r) {
            int j = h * JR + r * 4 + w;
            float4 av0 = *(const float4*)&attT[j][0];    // wave-uniform broadcast
            float4 av1 = *(const float4*)&attT[j][4];
            float4 xv  = *(const float4*)&xvl[j][0];
            float4 vv;
            vv.x = pf[r].x + xv.x; vv.y = pf[r].y + xv.y;
            vv.z = pf[r].z + xv.z; vv.w = pf[r].w + xv.w;
            acc4[0].x += av0.x * vv.x; acc4[0].y += av0.x * vv.y;
            acc4[0].z += av0.x * vv.z; acc4[0].w += av0.x * vv.w;
            acc4[1].x += av0.y * vv.x; acc4[1].y += av0.y * vv.y;
            acc4[1].z += av0.y * vv.z; acc4[1].w += av0.y * vv.w;
            acc4[2].x += av0.z * vv.x; acc4[2].y += av0.z * vv.y;
            acc4[2].z += av0.z * vv.z; acc4[2].w += av0.z * vv.w;
            acc4[3].x += av0.w * vv.x; acc4[3].y += av0.w * vv.y;
            acc4[3].z += av0.w * vv.z; acc4[3].w += av0.w * vv.w;
            acc4[4].x += av1.x * vv.x; acc4[4].y += av1.x * vv.y;
            acc4[4].z += av1.x * vv.z; acc4[4].w += av1.x * vv.w;
            acc4[5].x += av1.y * vv.x; acc4[5].y += av1.y * vv.y;
            acc4[5].z += av1.y * vv.z; acc4[5].w += av1.y * vv.w;
            acc4[6].x += av1.z * vv.x; acc4[6].y += av1.z * vv.y;
            acc4[6].z += av1.z * vv.z; acc4[6].w += av1.z * vv.w;
            acc4[7].x += av1.w * vv.x; acc4[7].y += av1.w * vv.y;
            acc4[7].z += av1.w * vv.z; acc4[7].w += av1.w * vv.w;
        }
        #pragma unroll
        for (int r = 0; r < 8; ++r) pf[r] = pfn[r];
    }

    // cross-wave reduction
    #pragma unroll
    for (int i = 0; i < ROWS; ++i)
        *(float4*)&red[w][i][tid & 63][0] = acc4[i];
    __syncthreads();

    float* ob = out + (size_t)(b * S + i0) * TC + tt * TCOLS + tid;
    #pragma unroll
    for (int i = 0; i < ROWS; ++i) {
        float o = red[0][i][tid >> 2][tid & 3] + red[1][i][tid >> 2][tid & 3]
                + red[2][i][tid >> 2][tid & 3] + red[3][i][tid >> 2][tid & 3];
        ob[i * TC] = o;
    }
}

extern "C" void kernel_launch(void* const* d_in, const int* in_sizes, int n_in,
                              void* d_out, int out_size, void* d_ws, size_t ws_size,
                              hipStream_t stream)
{
    const float* query  = (const float*)d_in[0];
    const float* key_in = (const float*)d_in[1];
    const float* value  = (const float*)d_in[2];
    const float* qw = (const float*)d_in[3];
    const float* qb = (const float*)d_in[4];
    const float* kw = (const float*)d_in[5];
    const float* kb = (const float*)d_in[6];
    const float* vw = (const float*)d_in[7];
    const float* vb = (const float*)d_in[8];
    float* out = (float*)d_out;

    float* Wv    = (float*)d_ws;
    float* SWq   = Wv + (size_t)S * TC;
    float* SWk   = SWq + S * 4;
    float* Gpart = SWk + S * 4;          // [KS][S][S] = 512 KB

    kA<<<256, 256, 0, stream>>>(qw, qb, kw, kb, vw, vb, Wv, SWq, SWk, Gpart);
    kB<<<dim3(TC / TCOLS, S / ROWS, B), 256, 0, stream>>>(
        query, key_in, value, Wv, SWq, SWk, Gpart, out);
}